// Round 3
// baseline (169.712 us; speedup 1.0000x reference)
//
#include <hip/hip_runtime.h>
#include <math.h>

#define LOG2E 1.44269504088896340736f

typedef _Float16 f16x8 __attribute__((ext_vector_type(8)));
typedef float f32x4 __attribute__((ext_vector_type(4)));

__device__ __forceinline__ float softplus_f(float t) {
    return (t > 20.0f) ? t : log1pf(expf(t));
}

// ---------------- pass 1: convert c -> f16 hi/lo, per-j scalars ----------------
// chi/clo: (M16 x 32) halves; sb[j] = { -0.5*log2e*|c_j|^2, beta_j }, zero-padded.
// beta pad = 0 so padded cols contribute nothing.
__global__ void prep_c_kernel(const float* __restrict__ c,
                              const float* __restrict__ beta,
                              _Float16* __restrict__ chi,
                              _Float16* __restrict__ clo,
                              float2* __restrict__ sb,
                              int M, int M16) {
    int j = blockIdx.x * blockDim.x + threadIdx.x;
    if (j >= M16) return;
    if (j < M) {
        const float4* cr = (const float4*)(c + (size_t)j * 32);
        float s = 0.0f;
#pragma unroll
        for (int q = 0; q < 8; ++q) {
            float4 v = cr[q];
            s = fmaf(v.x, v.x, s); s = fmaf(v.y, v.y, s);
            s = fmaf(v.z, v.z, s); s = fmaf(v.w, v.w, s);
            float vv[4] = {v.x, v.y, v.z, v.w};
#pragma unroll
            for (int t = 0; t < 4; ++t) {
                float f = vv[t];
                _Float16 h = (_Float16)f;
                chi[(size_t)j * 32 + q * 4 + t] = h;
                clo[(size_t)j * 32 + q * 4 + t] = (_Float16)(f - (float)h);
            }
        }
        sb[j] = make_float2(-0.5f * LOG2E * s, beta[j]);
    } else {
#pragma unroll
        for (int t = 0; t < 32; ++t) {
            chi[(size_t)j * 32 + t] = (_Float16)0.0f;
            clo[(size_t)j * 32 + t] = (_Float16)0.0f;
        }
        sb[j] = make_float2(0.0f, 0.0f);
    }
}

// ---------------- main: fully fused MFMA RBF matvec + softplus ----------------
// Block = 4 waves; wave w owns i-tile (blockIdx.x*4 + w) = 16 output rows,
// iterating over ALL j-tiles (no split -> no atomics, softplus fused, direct
// store). 4 waves/block walk the same B stream near-lockstep -> L1 reuse.
// Per j-tile: cross = x_hi*c_hi + x_lo*c_hi + x_hi*c_lo (x pre-scaled log2e),
// out_row += beta_j * exp2(cross + a_i + s_j).
// C layout (m89): col = lane&15, row = (lane>>4)*4 + reg.
__global__ __launch_bounds__(256) void krr_mfma_fused_kernel(
    const float* __restrict__ x,
    const _Float16* __restrict__ chi,
    const _Float16* __restrict__ clo,
    const float2* __restrict__ sb,
    float* __restrict__ out,
    int N, int JT)
{
    const int wave = threadIdx.x >> 6;
    const int lane = threadIdx.x & 63;
    const int m    = lane & 15;
    const int quad = lane >> 4;
    const int kbase = quad * 8;

    const int itile = blockIdx.x * 4 + wave;
    if (itile * 16 >= N) return;               // wave-uniform exit, no barriers used
    const int i = itile * 16 + m;
    const int iclamped = (i < N) ? i : (N - 1);

    // ---- A fragments: lane (m,quad) holds x[row m][k = quad*8 .. quad*8+7] ----
    const float4* xp = (const float4*)(x + (size_t)iclamped * 32 + kbase);
    float4 v0 = xp[0], v1 = xp[1];
    float p = v0.x * v0.x + v0.y * v0.y + v0.z * v0.z + v0.w * v0.w
            + v1.x * v1.x + v1.y * v1.y + v1.z * v1.z + v1.w * v1.w;
    p += __shfl_xor(p, 16, 64);
    p += __shfl_xor(p, 32, 64);                // |x_row(m)|^2, replicated over quads
    const float ai_m = -0.5f * LOG2E * p;      // a_i for row index m

    f16x8 ahi, alo;
    {
        float vv[8] = {v0.x, v0.y, v0.z, v0.w, v1.x, v1.y, v1.z, v1.w};
#pragma unroll
        for (int t = 0; t < 8; ++t) {
            float sv = vv[t] * LOG2E;
            _Float16 h = (_Float16)sv;
            ahi[t] = h;
            alo[t] = (_Float16)(sv - (float)h);
        }
    }
    // C-fragment row r of this lane is tile-row quad*4+r -> fetch its a_i by shuffle
    float air[4];
#pragma unroll
    for (int r = 0; r < 4; ++r)
        air[r] = __shfl(ai_m, quad * 4 + r, 16);   // width-16: segment-local src lane

    // ---- hot loop over all j-tiles ----
    float outacc[4] = {0.0f, 0.0f, 0.0f, 0.0f};
    const size_t lbase = (size_t)m * 32 + kbase;
#pragma unroll 4
    for (int jt = 0; jt < JT; ++jt) {
        const size_t boff = (size_t)jt * 512 + lbase;   // 16 rows * 32 halves per tile
        f16x8 bhi = *(const f16x8*)(chi + boff);
        f16x8 blo = *(const f16x8*)(clo + boff);
        const float2 s2 = sb[jt * 16 + m];              // {s_j, beta_j} for col m
        f32x4 acc = {0.0f, 0.0f, 0.0f, 0.0f};
        acc = __builtin_amdgcn_mfma_f32_16x16x32_f16(ahi, bhi, acc, 0, 0, 0);
        acc = __builtin_amdgcn_mfma_f32_16x16x32_f16(alo, bhi, acc, 0, 0, 0);
        acc = __builtin_amdgcn_mfma_f32_16x16x32_f16(ahi, blo, acc, 0, 0, 0);
#pragma unroll
        for (int r = 0; r < 4; ++r) {
            float e = __builtin_amdgcn_exp2f(acc[r] + air[r] + s2.x);
            outacc[r] = fmaf(s2.y, e, outacc[r]);
        }
    }

    // ---- reduce over the 16 cols (lanes differing in bits 0..3), store + softplus ----
#pragma unroll
    for (int r = 0; r < 4; ++r) {
        float v = outacc[r];
        v += __shfl_xor(v, 1, 64);
        v += __shfl_xor(v, 2, 64);
        v += __shfl_xor(v, 4, 64);
        v += __shfl_xor(v, 8, 64);
        if (m == r) {                           // spread the 4 stores over 4 lanes/segment
            int row = itile * 16 + quad * 4 + r;
            if (row < N) out[row] = softplus_f(v);
        }
    }
}

// ---------------- fallback path (ws too small): round-1 VALU kernel ----------------
#define CHUNK_MAX 512
__global__ void zero_out_kernel(float* __restrict__ out, int n) {
    int i = blockIdx.x * blockDim.x + threadIdx.x;
    if (i < n) out[i] = 0.0f;
}
__global__ void softplus_kernel(float* __restrict__ out, int n) {
    int i = blockIdx.x * blockDim.x + threadIdx.x;
    if (i < n) out[i] = softplus_f(out[i]);
}
__global__ __launch_bounds__(64, 4) void krr_partial_kernel(
    const float* __restrict__ x, const float* __restrict__ c,
    const float* __restrict__ beta, float* __restrict__ out,
    int N, int M, int chunk)
{
    __shared__ float2 sw[CHUNK_MAX];
    const int lane = threadIdx.x;
    const int j0 = blockIdx.y * chunk;
    const int j1 = min(M, j0 + chunk);
    for (int j = j0 + lane; j < j1; j += 64) {
        const float4* cr = (const float4*)(c + (size_t)j * 32);
        float s = 0.0f;
#pragma unroll
        for (int q = 0; q < 8; ++q) {
            float4 v = cr[q];
            s = fmaf(v.x, v.x, s); s = fmaf(v.y, v.y, s);
            s = fmaf(v.z, v.z, s); s = fmaf(v.w, v.w, s);
        }
        sw[j - j0] = make_float2(-0.5f * LOG2E * s, beta[j]);
    }
    __syncthreads();
    const int i = blockIdx.x * 64 + lane;
    const bool valid = (i < N);
    const float4* xrow = (const float4*)(x + (size_t)(valid ? i : 0) * 32);
    float xr[32]; float xsq = 0.0f;
#pragma unroll
    for (int q = 0; q < 8; ++q) {
        float4 v = xrow[q];
        xsq = fmaf(v.x, v.x, xsq); xsq = fmaf(v.y, v.y, xsq);
        xsq = fmaf(v.z, v.z, xsq); xsq = fmaf(v.w, v.w, xsq);
        xr[4*q+0] = v.x * LOG2E; xr[4*q+1] = v.y * LOG2E;
        xr[4*q+2] = v.z * LOG2E; xr[4*q+3] = v.w * LOG2E;
    }
    const float ai = -0.5f * LOG2E * xsq;
    float acc = 0.0f;
#pragma unroll 2
    for (int j = j0; j < j1; ++j) {
        const float4* cr = (const float4*)(c + (size_t)j * 32);
        const float2 s2 = sw[j - j0];
        float d = ai + s2.x;
#pragma unroll
        for (int q = 0; q < 8; ++q) {
            float4 v = cr[q];
            d = fmaf(xr[4*q+0], v.x, d); d = fmaf(xr[4*q+1], v.y, d);
            d = fmaf(xr[4*q+2], v.z, d); d = fmaf(xr[4*q+3], v.w, d);
        }
        acc = fmaf(s2.y, __builtin_amdgcn_exp2f(d), acc);
    }
    if (valid) atomicAdd(out + i, acc);
}

extern "C" void kernel_launch(void* const* d_in, const int* in_sizes, int n_in,
                              void* d_out, int out_size, void* d_ws, size_t ws_size,
                              hipStream_t stream) {
    const float* x    = (const float*)d_in[0];   // (N, 32)
    const float* c    = (const float*)d_in[1];   // (M, 32)
    const float* beta = (const float*)d_in[2];   // (M,)
    float* out = (float*)d_out;                  // (N,)

    const int N = out_size;        // 40000
    const int M = in_sizes[2];     // 4000
    const int M16 = ((M + 15) / 16) * 16;
    const int JT = M16 / 16;

    // ws layout: chi (M16*32 halves) | clo (M16*32 halves) | sb (M16 float2)
    const size_t need = (size_t)M16 * 32 * 2 * 2 + (size_t)M16 * 8;

    if (ws_size >= need) {
        _Float16* chi = (_Float16*)d_ws;
        _Float16* clo = chi + (size_t)M16 * 32;
        float2*   sb  = (float2*)(clo + (size_t)M16 * 32);

        prep_c_kernel<<<dim3((M16 + 255) / 256), dim3(256), 0, stream>>>(
            c, beta, chi, clo, sb, M, M16);

        const int itiles = (N + 15) / 16;            // 2500
        const int bx = (itiles + 3) / 4;             // 625 blocks x 4 waves
        krr_mfma_fused_kernel<<<dim3(bx), dim3(256), 0, stream>>>(
            x, chi, clo, sb, out, N, JT);
    } else {
        zero_out_kernel<<<dim3((N + 255) / 256), dim3(256), 0, stream>>>(out, N);
        int jc = (M + CHUNK_MAX - 1) / CHUNK_MAX;
        if (jc < 8) jc = 8;
        int chunk = (M + jc - 1) / jc;
        dim3 grid((N + 63) / 64, jc);
        krr_partial_kernel<<<grid, dim3(64), 0, stream>>>(x, c, beta, out, N, M, chunk);
        softplus_kernel<<<dim3((N + 255) / 256), dim3(256), 0, stream>>>(out, N);
    }
}

// Round 4
// 116.000 us; speedup vs baseline: 1.4630x; 1.4630x over previous
//
#include <hip/hip_runtime.h>
#include <math.h>
#include <stdint.h>

#define LOG2E 1.44269504088896340736f

typedef _Float16 f16x8 __attribute__((ext_vector_type(8)));
typedef float f32x4 __attribute__((ext_vector_type(4)));

__device__ __forceinline__ float softplus_f(float t) {
    return (t > 20.0f) ? t : log1pf(expf(t));
}

// global -> LDS direct DMA, 16 B/lane. lds base must be wave-uniform; HW adds lane*16.
#define GLDS16(g, l)                                                     \
    __builtin_amdgcn_global_load_lds(                                    \
        (const __attribute__((address_space(1))) uint32_t*)(const void*)(g), \
        (__attribute__((address_space(3))) uint32_t*)(void*)(l), 16, 0, 0)

// ---------------- pass 1: build fragment-linear B workspace ----------------
// For tile jt, fragment position l = q*16 + m (q = lane>>4, m = lane&15) holds
// c[j = jt*16+m][k = q*8 .. q*8+7] as f16 hi/lo. So a wave's B-fragment load is
// chiF + jt*512 + lane*8 halves == base + lane*16 B: dense, DMA-compatible.
// sbG[j] = { -0.5*log2e*|c_j|^2, beta_j }, zero-padded (beta=0 kills pad cols).
// One thread per (j, q): 16384 threads.
__global__ void prep_c_kernel(const float* __restrict__ c,
                              const float* __restrict__ beta,
                              _Float16* __restrict__ chiF,
                              _Float16* __restrict__ cloF,
                              float2* __restrict__ sbG,
                              int M, int Mp) {
    int tid = blockIdx.x * blockDim.x + threadIdx.x;
    int j = tid >> 2, q = tid & 3;
    if (j >= Mp) return;
    int jt = j >> 4, m = j & 15;
    size_t fo = (size_t)jt * 512 + (size_t)(q * 16 + m) * 8;   // halves

    float ssq = 0.0f;
    _Float16 hi[8], lo[8];
    if (j < M) {
        const float4* cp = (const float4*)(c + (size_t)j * 32 + q * 8);
        float4 a = cp[0], b = cp[1];
        float vv[8] = {a.x, a.y, a.z, a.w, b.x, b.y, b.z, b.w};
#pragma unroll
        for (int t = 0; t < 8; ++t) {
            float f = vv[t];
            ssq = fmaf(f, f, ssq);
            _Float16 h = (_Float16)f;
            hi[t] = h;
            lo[t] = (_Float16)(f - (float)h);
        }
    } else {
#pragma unroll
        for (int t = 0; t < 8; ++t) { hi[t] = (_Float16)0.0f; lo[t] = (_Float16)0.0f; }
    }
    // |c_j|^2: reduce over the 4 q-threads (consecutive lanes)
    ssq += __shfl_xor(ssq, 1, 4);
    ssq += __shfl_xor(ssq, 2, 4);

    *(f16x8*)(chiF + fo) = *(const f16x8*)hi;
    *(f16x8*)(cloF + fo) = *(const f16x8*)lo;
    if (q == 0)
        sbG[j] = (j < M) ? make_float2(-0.5f * LOG2E * ssq, beta[j])
                         : make_float2(0.0f, 0.0f);
}

// ---------------- main: LDS-staged, double-buffered MFMA RBF matvec ----------------
// Block = 4 waves; wave w owns i-tile blockIdx.x*4+w (16 rows), sweeps ALL j-tiles.
// Super-step = 8 j-tiles staged in LDS (17 KB/buffer) shared by the 4 waves ->
// 4x less L1/L2 traffic than per-wave loads. DMA for step s+1 issued right after
// the barrier that opens compute of step s -> its vmcnt drain (at the next
// barrier) lands a full compute-phase later: real overlap.
// C layout (m89): col = lane&15, row = (lane>>4)*4 + reg.
__global__ __launch_bounds__(256) void krr_mfma_lds_kernel(
    const float* __restrict__ x,
    const _Float16* __restrict__ chiF,
    const _Float16* __restrict__ cloF,
    const float2* __restrict__ sbG,
    float* __restrict__ out,
    int N, int steps)
{
    __shared__ f16x8 chiS[2][8][64];             // 16 KB
    __shared__ f16x8 cloS[2][8][64];             // 16 KB
    __shared__ __align__(16) float2 sbS[2][128]; // 2 KB

    const int wave = threadIdx.x >> 6;
    const int lane = threadIdx.x & 63;
    const int m    = lane & 15;
    const int quad = lane >> 4;

    const int itile = blockIdx.x * 4 + wave;
    const int i = itile * 16 + m;
    const int iclamped = (i < N) ? i : (N - 1);   // no early exit: barriers need all waves

    // ---- A fragments (lane (m,quad): x[row m][k=quad*8..+7], pre-scaled log2e) ----
    const float4* xp = (const float4*)(x + (size_t)iclamped * 32 + quad * 8);
    float4 v0 = xp[0], v1 = xp[1];
    float p = v0.x * v0.x + v0.y * v0.y + v0.z * v0.z + v0.w * v0.w
            + v1.x * v1.x + v1.y * v1.y + v1.z * v1.z + v1.w * v1.w;
    p += __shfl_xor(p, 16, 64);
    p += __shfl_xor(p, 32, 64);                  // |x_row(m)|^2 over all quads
    const float ai_m = -0.5f * LOG2E * p;

    f16x8 ahi, alo;
    {
        float vv[8] = {v0.x, v0.y, v0.z, v0.w, v1.x, v1.y, v1.z, v1.w};
#pragma unroll
        for (int t = 0; t < 8; ++t) {
            float sv = vv[t] * LOG2E;
            _Float16 h = (_Float16)sv;
            ahi[t] = h;
            alo[t] = (_Float16)(sv - (float)h);
        }
    }
    float air[4];
#pragma unroll
    for (int r = 0; r < 4; ++r)
        air[r] = __shfl(ai_m, quad * 4 + r, 16);   // a_i for C-fragment row quad*4+r

    // ---- staging: 17 chunks/step (8 chi + 8 clo + 1 sb), distributed over waves ----
    auto stage = [&](int s, int b) {
        const size_t tbase = (size_t)s * 8 * 512;  // halves
#pragma unroll
        for (int ch = wave; ch < 16; ch += 4) {
            const int t = ch & 7;
            if (ch < 8) {
                GLDS16(chiF + tbase + (size_t)t * 512 + (size_t)lane * 8, &chiS[b][t][0]);
            } else {
                GLDS16(cloF + tbase + (size_t)t * 512 + (size_t)lane * 8, &cloS[b][t][0]);
            }
        }
        if (wave == 0) {
            GLDS16((const char*)(sbG + (size_t)s * 128) + (size_t)lane * 16, &sbS[b][0]);
        }
    };

    stage(0, 0);
    float outacc[4] = {0.0f, 0.0f, 0.0f, 0.0f};

    for (int s = 0; s < steps; ++s) {
        const int b = s & 1;
        __syncthreads();                 // drains stage(s) DMA; guards buffer b^1 reuse
        if (s + 1 < steps) stage(s + 1, b ^ 1);

#pragma unroll
        for (int t = 0; t < 8; ++t) {
            f16x8 bhi = chiS[b][t][lane];           // ds_read_b128, lane-linear: conflict-free
            f16x8 blo = cloS[b][t][lane];
            float2 s2 = sbS[b][t * 16 + m];         // {s_j, beta_j} for col m
            f32x4 acc;
#pragma unroll
            for (int r = 0; r < 4; ++r) acc[r] = air[r] + s2.x;   // fold a_i + s_j into C init
            acc = __builtin_amdgcn_mfma_f32_16x16x32_f16(ahi, bhi, acc, 0, 0, 0);
            acc = __builtin_amdgcn_mfma_f32_16x16x32_f16(alo, bhi, acc, 0, 0, 0);
            acc = __builtin_amdgcn_mfma_f32_16x16x32_f16(ahi, blo, acc, 0, 0, 0);
#pragma unroll
            for (int r = 0; r < 4; ++r)
                outacc[r] = fmaf(s2.y, __builtin_amdgcn_exp2f(acc[r]), outacc[r]);
        }
    }

    // ---- reduce over 16 cols (lane bits 0..3), fused softplus store ----
#pragma unroll
    for (int r = 0; r < 4; ++r) {
        float v = outacc[r];
        v += __shfl_xor(v, 1, 64);
        v += __shfl_xor(v, 2, 64);
        v += __shfl_xor(v, 4, 64);
        v += __shfl_xor(v, 8, 64);
        if (m == r) {
            int row = itile * 16 + quad * 4 + r;
            if (row < N) out[row] = softplus_f(v);
        }
    }
}

// ---------------- fallback path (ws too small): round-1 VALU kernel ----------------
#define CHUNK_MAX 512
__global__ void zero_out_kernel(float* __restrict__ out, int n) {
    int i = blockIdx.x * blockDim.x + threadIdx.x;
    if (i < n) out[i] = 0.0f;
}
__global__ void softplus_kernel(float* __restrict__ out, int n) {
    int i = blockIdx.x * blockDim.x + threadIdx.x;
    if (i < n) out[i] = softplus_f(out[i]);
}
__global__ __launch_bounds__(64, 4) void krr_partial_kernel(
    const float* __restrict__ x, const float* __restrict__ c,
    const float* __restrict__ beta, float* __restrict__ out,
    int N, int M, int chunk)
{
    __shared__ float2 sw[CHUNK_MAX];
    const int lane = threadIdx.x;
    const int j0 = blockIdx.y * chunk;
    const int j1 = min(M, j0 + chunk);
    for (int j = j0 + lane; j < j1; j += 64) {
        const float4* cr = (const float4*)(c + (size_t)j * 32);
        float s = 0.0f;
#pragma unroll
        for (int q = 0; q < 8; ++q) {
            float4 v = cr[q];
            s = fmaf(v.x, v.x, s); s = fmaf(v.y, v.y, s);
            s = fmaf(v.z, v.z, s); s = fmaf(v.w, v.w, s);
        }
        sw[j - j0] = make_float2(-0.5f * LOG2E * s, beta[j]);
    }
    __syncthreads();
    const int i = blockIdx.x * 64 + lane;
    const bool valid = (i < N);
    const float4* xrow = (const float4*)(x + (size_t)(valid ? i : 0) * 32);
    float xr[32]; float xsq = 0.0f;
#pragma unroll
    for (int q = 0; q < 8; ++q) {
        float4 v = xrow[q];
        xsq = fmaf(v.x, v.x, xsq); xsq = fmaf(v.y, v.y, xsq);
        xsq = fmaf(v.z, v.z, xsq); xsq = fmaf(v.w, v.w, xsq);
        xr[4*q+0] = v.x * LOG2E; xr[4*q+1] = v.y * LOG2E;
        xr[4*q+2] = v.z * LOG2E; xr[4*q+3] = v.w * LOG2E;
    }
    const float ai = -0.5f * LOG2E * xsq;
    float acc = 0.0f;
#pragma unroll 2
    for (int j = j0; j < j1; ++j) {
        const float4* cr = (const float4*)(c + (size_t)j * 32);
        const float2 s2 = sw[j - j0];
        float d = ai + s2.x;
#pragma unroll
        for (int q = 0; q < 8; ++q) {
            float4 v = cr[q];
            d = fmaf(xr[4*q+0], v.x, d); d = fmaf(xr[4*q+1], v.y, d);
            d = fmaf(xr[4*q+2], v.z, d); d = fmaf(xr[4*q+3], v.w, d);
        }
        acc = fmaf(s2.y, __builtin_amdgcn_exp2f(d), acc);
    }
    if (valid) atomicAdd(out + i, acc);
}

extern "C" void kernel_launch(void* const* d_in, const int* in_sizes, int n_in,
                              void* d_out, int out_size, void* d_ws, size_t ws_size,
                              hipStream_t stream) {
    const float* x    = (const float*)d_in[0];   // (N, 32)
    const float* c    = (const float*)d_in[1];   // (M, 32)
    const float* beta = (const float*)d_in[2];   // (M,)
    float* out = (float*)d_out;                  // (N,)

    const int N = out_size;                  // 40000
    const int M = in_sizes[2];               // 4000
    const int JT = (M + 15) / 16;            // 250 j-tiles
    const int JTS = ((JT + 7) / 8) * 8;      // padded to super-step multiple: 256
    const int steps = JTS / 8;               // 32
    const int Mp = JTS * 16;                 // 4096 padded cols

    // ws: chiF | cloF (JTS*512 halves each, fragment-linear) | sbG (Mp float2)
    const size_t need = (size_t)JTS * 1024 * 2 + (size_t)Mp * 8;   // 544 KB

    if (ws_size >= need) {
        _Float16* chiF = (_Float16*)d_ws;
        _Float16* cloF = chiF + (size_t)JTS * 512;
        float2*   sbG  = (float2*)(cloF + (size_t)JTS * 512);

        prep_c_kernel<<<dim3((Mp * 4 + 255) / 256), dim3(256), 0, stream>>>(
            c, beta, chiF, cloF, sbG, M, Mp);

        const int itiles = (N + 15) / 16;            // 2500
        const int bx = (itiles + 3) / 4;             // 625 blocks x 4 waves
        krr_mfma_lds_kernel<<<dim3(bx), dim3(256), 0, stream>>>(
            x, chiF, cloF, sbG, out, N, steps);
    } else {
        zero_out_kernel<<<dim3((N + 255) / 256), dim3(256), 0, stream>>>(out, N);
        int jc = (M + CHUNK_MAX - 1) / CHUNK_MAX;
        if (jc < 8) jc = 8;
        int chunk = (M + jc - 1) / jc;
        dim3 grid((N + 63) / 64, jc);
        krr_partial_kernel<<<grid, dim3(64), 0, stream>>>(x, c, beta, out, N, M, chunk);
        softplus_kernel<<<dim3((N + 255) / 256), dim3(256), 0, stream>>>(out, N);
    }
}

// Round 5
// 103.429 us; speedup vs baseline: 1.6408x; 1.1215x over previous
//
#include <hip/hip_runtime.h>
#include <math.h>
#include <stdint.h>

#define LOG2E 1.44269504088896340736f
#define TPS 16   // j-tiles per super-step

typedef _Float16 f16x8 __attribute__((ext_vector_type(8)));
typedef float f32x4 __attribute__((ext_vector_type(4)));

__device__ __forceinline__ float softplus_f(float t) {
    return (t > 20.0f) ? t : log1pf(expf(t));
}

// global -> LDS direct DMA, 16 B/lane. lds base must be wave-uniform; HW adds lane*16.
#define GLDS16(g, l)                                                     \
    __builtin_amdgcn_global_load_lds(                                    \
        (const __attribute__((address_space(1))) uint32_t*)(const void*)(g), \
        (__attribute__((address_space(3))) uint32_t*)(void*)(l), 16, 0, 0)

// ---------------- pass 1: build fragment-linear f16 B workspace ----------------
// Single-term f16 is numerically sufficient here: K errors ~1% x K_max ~0.02
// -> output error ~2e-4 << 1.39e-2 threshold (outputs ~ softplus of tiny sums).
// Tile jt, fragment position l = q*16+m holds c[j=jt*16+m][k=q*8..q*8+7] as f16,
// so a wave's B-fragment load is base + lane*16 B: dense, DMA-compatible.
// sbG[j] = { -0.5*log2e*|c_j|^2, beta_j }, zero-padded (beta=0 kills pad cols).
__global__ void prep_c_kernel(const float* __restrict__ c,
                              const float* __restrict__ beta,
                              _Float16* __restrict__ chiF,
                              float2* __restrict__ sbG,
                              int M, int Mp) {
    int tid = blockIdx.x * blockDim.x + threadIdx.x;
    int j = tid >> 2, q = tid & 3;
    if (j >= Mp) return;
    int jt = j >> 4, m = j & 15;
    size_t fo = (size_t)jt * 512 + (size_t)(q * 16 + m) * 8;   // halves

    float ssq = 0.0f;
    _Float16 hi[8];
    if (j < M) {
        const float4* cp = (const float4*)(c + (size_t)j * 32 + q * 8);
        float4 a = cp[0], b = cp[1];
        float vv[8] = {a.x, a.y, a.z, a.w, b.x, b.y, b.z, b.w};
#pragma unroll
        for (int t = 0; t < 8; ++t) {
            float f = vv[t];
            ssq = fmaf(f, f, ssq);
            hi[t] = (_Float16)f;
        }
    } else {
#pragma unroll
        for (int t = 0; t < 8; ++t) hi[t] = (_Float16)0.0f;
    }
    // |c_j|^2: reduce over the 4 q-threads (consecutive lanes)
    ssq += __shfl_xor(ssq, 1, 4);
    ssq += __shfl_xor(ssq, 2, 4);

    *(f16x8*)(chiF + fo) = *(const f16x8*)hi;
    if (q == 0)
        sbG[j] = (j < M) ? make_float2(-0.5f * LOG2E * ssq, beta[j])
                         : make_float2(0.0f, 0.0f);
}

// ---------------- main: LDS-staged, double-buffered MFMA RBF matvec ----------------
// Block = 4 waves; wave w owns i-tile blockIdx.x*4+w (16 rows), sweeps ALL j-tiles.
// Super-step = 16 j-tiles (18 KB/buffer) staged via global_load_lds and shared by
// the 4 waves. DMA for step s+1 issues right after the barrier opening step s ->
// its drain lands a full compute-phase later. Full unroll over the 16 tiles turns
// VGPR headroom into prefetch depth (the round-4 kernel had VGPR=52 and a serial
// load->wait->use loop; that was the 57% idle).
// C layout (m89): col = lane&15, row = (lane>>4)*4 + reg.
__global__ __launch_bounds__(256) void krr_mfma_lds_kernel(
    const float* __restrict__ x,
    const _Float16* __restrict__ chiF,
    const float2* __restrict__ sbG,
    float* __restrict__ out,
    int N, int steps)
{
    __shared__ f16x8 chiS[2][TPS][64];               // 32 KB
    __shared__ __align__(16) float2 sbS[2][TPS * 16]; // 4 KB

    const int wave = threadIdx.x >> 6;
    const int lane = threadIdx.x & 63;
    const int m    = lane & 15;
    const int quad = lane >> 4;

    const int itile = blockIdx.x * 4 + wave;
    const int i = itile * 16 + m;
    const int iclamped = (i < N) ? i : (N - 1);   // no early exit: barriers need all waves

    // ---- A fragment (lane (m,quad): x[row m][k=quad*8..+7], pre-scaled log2e) ----
    const float4* xp = (const float4*)(x + (size_t)iclamped * 32 + quad * 8);
    float4 v0 = xp[0], v1 = xp[1];
    float p = v0.x * v0.x + v0.y * v0.y + v0.z * v0.z + v0.w * v0.w
            + v1.x * v1.x + v1.y * v1.y + v1.z * v1.z + v1.w * v1.w;
    p += __shfl_xor(p, 16, 64);
    p += __shfl_xor(p, 32, 64);                   // |x_row(m)|^2 over all quads
    const float ai_m = -0.5f * LOG2E * p;

    f16x8 ahi;
    {
        float vv[8] = {v0.x, v0.y, v0.z, v0.w, v1.x, v1.y, v1.z, v1.w};
#pragma unroll
        for (int t = 0; t < 8; ++t)
            ahi[t] = (_Float16)(vv[t] * LOG2E);
    }
    float air[4];
#pragma unroll
    for (int r = 0; r < 4; ++r)
        air[r] = __shfl(ai_m, quad * 4 + r, 16);  // a_i for C-fragment row quad*4+r

    // ---- staging: 16 chi chunks + 2 sb chunks per step, spread over 4 waves ----
    auto stage = [&](int s, int b) {
        const _Float16* base = chiF + (size_t)s * TPS * 512;
#pragma unroll
        for (int ch = wave; ch < TPS; ch += 4)
            GLDS16(base + (size_t)ch * 512 + (size_t)lane * 8, &chiS[b][ch][0]);
        if (wave < 2)
            GLDS16((const char*)(sbG + (size_t)s * (TPS * 16)) +
                       (size_t)(wave * 64 + lane) * 16,
                   &sbS[b][wave * 128]);
    };

    stage(0, 0);
    float outacc[4] = {0.0f, 0.0f, 0.0f, 0.0f};

    for (int s = 0; s < steps; ++s) {
        const int b = s & 1;
        __syncthreads();                 // drains stage(s) DMA; guards buffer b^1 reuse
        if (s + 1 < steps) stage(s + 1, b ^ 1);

#pragma unroll
        for (int t = 0; t < TPS; ++t) {
            f16x8 bhi = chiS[b][t][lane];           // ds_read_b128, lane-linear
            float2 s2 = sbS[b][t * 16 + m];         // {s_j, beta_j}, 4-way broadcast
            f32x4 acc;
#pragma unroll
            for (int r = 0; r < 4; ++r) acc[r] = air[r] + s2.x;  // fold a_i+s_j into C
            acc = __builtin_amdgcn_mfma_f32_16x16x32_f16(ahi, bhi, acc, 0, 0, 0);
#pragma unroll
            for (int r = 0; r < 4; ++r)
                outacc[r] = fmaf(s2.y, __builtin_amdgcn_exp2f(acc[r]), outacc[r]);
        }
    }

    // ---- reduce over 16 cols (lane bits 0..3), fused softplus store ----
#pragma unroll
    for (int r = 0; r < 4; ++r) {
        float v = outacc[r];
        v += __shfl_xor(v, 1, 64);
        v += __shfl_xor(v, 2, 64);
        v += __shfl_xor(v, 4, 64);
        v += __shfl_xor(v, 8, 64);
        if (m == r) {
            int row = itile * 16 + quad * 4 + r;
            if (row < N) out[row] = softplus_f(v);
        }
    }
}

// ---------------- fallback path (ws too small): round-1 VALU kernel ----------------
#define CHUNK_MAX 512
__global__ void zero_out_kernel(float* __restrict__ out, int n) {
    int i = blockIdx.x * blockDim.x + threadIdx.x;
    if (i < n) out[i] = 0.0f;
}
__global__ void softplus_kernel(float* __restrict__ out, int n) {
    int i = blockIdx.x * blockDim.x + threadIdx.x;
    if (i < n) out[i] = softplus_f(out[i]);
}
__global__ __launch_bounds__(64, 4) void krr_partial_kernel(
    const float* __restrict__ x, const float* __restrict__ c,
    const float* __restrict__ beta, float* __restrict__ out,
    int N, int M, int chunk)
{
    __shared__ float2 sw[CHUNK_MAX];
    const int lane = threadIdx.x;
    const int j0 = blockIdx.y * chunk;
    const int j1 = min(M, j0 + chunk);
    for (int j = j0 + lane; j < j1; j += 64) {
        const float4* cr = (const float4*)(c + (size_t)j * 32);
        float s = 0.0f;
#pragma unroll
        for (int q = 0; q < 8; ++q) {
            float4 v = cr[q];
            s = fmaf(v.x, v.x, s); s = fmaf(v.y, v.y, s);
            s = fmaf(v.z, v.z, s); s = fmaf(v.w, v.w, s);
        }
        sw[j - j0] = make_float2(-0.5f * LOG2E * s, beta[j]);
    }
    __syncthreads();
    const int i = blockIdx.x * 64 + lane;
    const bool valid = (i < N);
    const float4* xrow = (const float4*)(x + (size_t)(valid ? i : 0) * 32);
    float xr[32]; float xsq = 0.0f;
#pragma unroll
    for (int q = 0; q < 8; ++q) {
        float4 v = xrow[q];
        xsq = fmaf(v.x, v.x, xsq); xsq = fmaf(v.y, v.y, xsq);
        xsq = fmaf(v.z, v.z, xsq); xsq = fmaf(v.w, v.w, xsq);
        xr[4*q+0] = v.x * LOG2E; xr[4*q+1] = v.y * LOG2E;
        xr[4*q+2] = v.z * LOG2E; xr[4*q+3] = v.w * LOG2E;
    }
    const float ai = -0.5f * LOG2E * xsq;
    float acc = 0.0f;
#pragma unroll 2
    for (int j = j0; j < j1; ++j) {
        const float4* cr = (const float4*)(c + (size_t)j * 32);
        const float2 s2 = sw[j - j0];
        float d = ai + s2.x;
#pragma unroll
        for (int q = 0; q < 8; ++q) {
            float4 v = cr[q];
            d = fmaf(xr[4*q+0], v.x, d); d = fmaf(xr[4*q+1], v.y, d);
            d = fmaf(xr[4*q+2], v.z, d); d = fmaf(xr[4*q+3], v.w, d);
        }
        acc = fmaf(s2.y, __builtin_amdgcn_exp2f(d), acc);
    }
    if (valid) atomicAdd(out + i, acc);
}

extern "C" void kernel_launch(void* const* d_in, const int* in_sizes, int n_in,
                              void* d_out, int out_size, void* d_ws, size_t ws_size,
                              hipStream_t stream) {
    const float* x    = (const float*)d_in[0];   // (N, 32)
    const float* c    = (const float*)d_in[1];   // (M, 32)
    const float* beta = (const float*)d_in[2];   // (M,)
    float* out = (float*)d_out;                  // (N,)

    const int N = out_size;                      // 40000
    const int M = in_sizes[2];                   // 4000
    const int JT = (M + 15) / 16;                // 250 j-tiles
    const int JTS = ((JT + TPS - 1) / TPS) * TPS; // padded: 256
    const int steps = JTS / TPS;                 // 16
    const int Mp = JTS * 16;                     // 4096 padded cols

    // ws: chiF (JTS*512 halves, fragment-linear) | sbG (Mp float2)  ~ 288 KB
    const size_t need = (size_t)JTS * 1024 + (size_t)Mp * 8;

    if (ws_size >= need) {
        _Float16* chiF = (_Float16*)d_ws;
        float2*   sbG  = (float2*)(chiF + (size_t)JTS * 512);

        prep_c_kernel<<<dim3((Mp * 4 + 255) / 256), dim3(256), 0, stream>>>(
            c, beta, chiF, sbG, M, Mp);

        const int itiles = (N + 15) / 16;            // 2500
        const int bx = (itiles + 3) / 4;             // 625 blocks x 4 waves
        krr_mfma_lds_kernel<<<dim3(bx), dim3(256), 0, stream>>>(
            x, chiF, sbG, out, N, steps);
    } else {
        zero_out_kernel<<<dim3((N + 255) / 256), dim3(256), 0, stream>>>(out, N);
        int jc = (M + CHUNK_MAX - 1) / CHUNK_MAX;
        if (jc < 8) jc = 8;
        int chunk = (M + jc - 1) / jc;
        dim3 grid((N + 63) / 64, jc);
        krr_partial_kernel<<<grid, dim3(64), 0, stream>>>(x, c, beta, out, N, M, chunk);
        softplus_kernel<<<dim3((N + 255) / 256), dim3(256), 0, stream>>>(out, N);
    }
}

// Round 6
// 95.962 us; speedup vs baseline: 1.7685x; 1.0778x over previous
//
#include <hip/hip_runtime.h>
#include <math.h>
#include <stdint.h>

#define LOG2E 1.44269504088896340736f
#define TPS 8    // j-tiles per super-step (18 KB LDS -> ~8 blocks/CU capacity)
#define JS  2    // j-range splits (x2 waves: 2.44 -> 4.88 waves/SIMD)

typedef _Float16 f16x8 __attribute__((ext_vector_type(8)));
typedef float f32x4 __attribute__((ext_vector_type(4)));

__device__ __forceinline__ float softplus_f(float t) {
    return (t > 20.0f) ? t : log1pf(expf(t));
}

// global -> LDS direct DMA, 16 B/lane. lds base must be wave-uniform; HW adds lane*16.
#define GLDS16(g, l)                                                     \
    __builtin_amdgcn_global_load_lds(                                    \
        (const __attribute__((address_space(1))) uint32_t*)(const void*)(g), \
        (__attribute__((address_space(3))) uint32_t*)(void*)(l), 16, 0, 0)

// ---------------- pass 1: fragment-linear f16 B workspace + out zero-init ----------------
// Single-term f16 suffices: K rel-err ~1% x K_max ~0.02 -> out err ~2e-4 << 1.39e-2.
// Tile jt, fragment pos l = q*16+m holds c[j=jt*16+m][k=q*8..q*8+7] as f16 ->
// wave B-load = base + lane*16 B (dense, DMA-compatible).
// sbG[j] = { -0.5*log2e*|c_j|^2, beta_j }, beta=0 on padding kills pad cols.
// Also zeroes out[] (atomicAdd accumulation target for the j-split main kernel).
__global__ void prep_c_kernel(const float* __restrict__ c,
                              const float* __restrict__ beta,
                              _Float16* __restrict__ chiF,
                              float2* __restrict__ sbG,
                              float* __restrict__ out,
                              int M, int Mp, int N) {
    int tid = blockIdx.x * blockDim.x + threadIdx.x;
    if (tid < N) out[tid] = 0.0f;

    int j = tid >> 2, q = tid & 3;
    if (j >= Mp) return;
    int jt = j >> 4, m = j & 15;
    size_t fo = (size_t)jt * 512 + (size_t)(q * 16 + m) * 8;   // halves

    float ssq = 0.0f;
    _Float16 hi[8];
    if (j < M) {
        const float4* cp = (const float4*)(c + (size_t)j * 32 + q * 8);
        float4 a = cp[0], b = cp[1];
        float vv[8] = {a.x, a.y, a.z, a.w, b.x, b.y, b.z, b.w};
#pragma unroll
        for (int t = 0; t < 8; ++t) {
            float f = vv[t];
            ssq = fmaf(f, f, ssq);
            hi[t] = (_Float16)f;
        }
    } else {
#pragma unroll
        for (int t = 0; t < 8; ++t) hi[t] = (_Float16)0.0f;
    }
    ssq += __shfl_xor(ssq, 1, 4);       // |c_j|^2 over the 4 q-threads
    ssq += __shfl_xor(ssq, 2, 4);

    *(f16x8*)(chiF + fo) = *(const f16x8*)hi;
    if (q == 0)
        sbG[j] = (j < M) ? make_float2(-0.5f * LOG2E * ssq, beta[j])
                         : make_float2(0.0f, 0.0f);
}

// ---------------- main: LDS-staged double-buffered MFMA RBF matvec ----------------
// Block = 4 waves; wave w owns i-tile blockIdx.x*4+w (16 rows); blockIdx.y picks a
// half of the j-tiles. Super-step = 8 j-tiles (9 KB/buffer) staged via
// global_load_lds, shared by the 4 waves. DMA for step s+1 issues right after the
// barrier opening step s. Partials accumulated to out[] with atomicAdd (2/row).
// C layout (m89): col = lane&15, row = (lane>>4)*4 + reg.
__global__ __launch_bounds__(256) void krr_mfma_lds_kernel(
    const float* __restrict__ x,
    const _Float16* __restrict__ chiF,
    const float2* __restrict__ sbG,
    float* __restrict__ out,
    int N, int steps)             // steps per j-split
{
    __shared__ f16x8 chiS[2][TPS][64];                // 16 KB
    __shared__ __align__(16) float2 sbS[2][TPS * 16]; // 2 KB

    const int wave = threadIdx.x >> 6;
    const int lane = threadIdx.x & 63;
    const int m    = lane & 15;
    const int quad = lane >> 4;

    const int itile = blockIdx.x * 4 + wave;
    const int i = itile * 16 + m;
    const int iclamped = (i < N) ? i : (N - 1);
    const int s0 = blockIdx.y * steps;                // this block's super-step range

    // ---- A fragment (lane (m,quad): x[row m][k=quad*8..+7], pre-scaled log2e) ----
    const float4* xp = (const float4*)(x + (size_t)iclamped * 32 + quad * 8);
    float4 v0 = xp[0], v1 = xp[1];
    float p = v0.x * v0.x + v0.y * v0.y + v0.z * v0.z + v0.w * v0.w
            + v1.x * v1.x + v1.y * v1.y + v1.z * v1.z + v1.w * v1.w;
    p += __shfl_xor(p, 16, 64);
    p += __shfl_xor(p, 32, 64);                       // |x_row(m)|^2 over all quads
    const float ai_m = -0.5f * LOG2E * p;

    f16x8 ahi;
    {
        float vv[8] = {v0.x, v0.y, v0.z, v0.w, v1.x, v1.y, v1.z, v1.w};
#pragma unroll
        for (int t = 0; t < 8; ++t)
            ahi[t] = (_Float16)(vv[t] * LOG2E);
    }
    float air[4];
#pragma unroll
    for (int r = 0; r < 4; ++r)
        air[r] = __shfl(ai_m, quad * 4 + r, 16);      // a_i for C-fragment row quad*4+r

    // ---- staging: 8 chi chunks (2/wave) + 1 sb chunk per step ----
    auto stage = [&](int s, int b) {
        const _Float16* base = chiF + (size_t)(s0 + s) * TPS * 512;
#pragma unroll
        for (int ch = wave; ch < TPS; ch += 4)
            GLDS16(base + (size_t)ch * 512 + (size_t)lane * 8, &chiS[b][ch][0]);
        if (wave == 0)
            GLDS16((const char*)(sbG + (size_t)(s0 + s) * (TPS * 16)) + (size_t)lane * 16,
                   &sbS[b][0]);
    };

    stage(0, 0);
    float outacc[4] = {0.0f, 0.0f, 0.0f, 0.0f};

    for (int s = 0; s < steps; ++s) {
        const int b = s & 1;
        __syncthreads();                 // drains stage(s) DMA; guards buffer b^1 reuse
        if (s + 1 < steps) stage(s + 1, b ^ 1);

#pragma unroll
        for (int t = 0; t < TPS; ++t) {
            f16x8 bhi = chiS[b][t][lane];             // ds_read_b128, lane-linear
            float2 s2 = sbS[b][t * 16 + m];           // {s_j, beta_j}, broadcast
            f32x4 acc;
#pragma unroll
            for (int r = 0; r < 4; ++r) acc[r] = air[r] + s2.x;  // fold a_i+s_j into C
            acc = __builtin_amdgcn_mfma_f32_16x16x32_f16(ahi, bhi, acc, 0, 0, 0);
#pragma unroll
            for (int r = 0; r < 4; ++r)
                outacc[r] = fmaf(s2.y, __builtin_amdgcn_exp2f(acc[r]), outacc[r]);
        }
    }

    // ---- reduce over 16 cols (lane bits 0..3), atomic partial-sum ----
#pragma unroll
    for (int r = 0; r < 4; ++r) {
        float v = outacc[r];
        v += __shfl_xor(v, 1, 64);
        v += __shfl_xor(v, 2, 64);
        v += __shfl_xor(v, 4, 64);
        v += __shfl_xor(v, 8, 64);
        if (m == r) {
            int row = itile * 16 + quad * 4 + r;
            if (row < N) atomicAdd(out + row, v);
        }
    }
}

// ---------------- pass 3: softplus over accumulated partials ----------------
__global__ void softplus_kernel(float* __restrict__ out, int n) {
    int i = blockIdx.x * blockDim.x + threadIdx.x;
    if (i < n) out[i] = softplus_f(out[i]);
}

// ---------------- fallback path (ws too small): round-1 VALU kernel ----------------
#define CHUNK_MAX 512
__global__ void zero_out_kernel(float* __restrict__ out, int n) {
    int i = blockIdx.x * blockDim.x + threadIdx.x;
    if (i < n) out[i] = 0.0f;
}
__global__ __launch_bounds__(64, 4) void krr_partial_kernel(
    const float* __restrict__ x, const float* __restrict__ c,
    const float* __restrict__ beta, float* __restrict__ out,
    int N, int M, int chunk)
{
    __shared__ float2 sw[CHUNK_MAX];
    const int lane = threadIdx.x;
    const int j0 = blockIdx.y * chunk;
    const int j1 = min(M, j0 + chunk);
    for (int j = j0 + lane; j < j1; j += 64) {
        const float4* cr = (const float4*)(c + (size_t)j * 32);
        float s = 0.0f;
#pragma unroll
        for (int q = 0; q < 8; ++q) {
            float4 v = cr[q];
            s = fmaf(v.x, v.x, s); s = fmaf(v.y, v.y, s);
            s = fmaf(v.z, v.z, s); s = fmaf(v.w, v.w, s);
        }
        sw[j - j0] = make_float2(-0.5f * LOG2E * s, beta[j]);
    }
    __syncthreads();
    const int i = blockIdx.x * 64 + lane;
    const bool valid = (i < N);
    const float4* xrow = (const float4*)(x + (size_t)(valid ? i : 0) * 32);
    float xr[32]; float xsq = 0.0f;
#pragma unroll
    for (int q = 0; q < 8; ++q) {
        float4 v = xrow[q];
        xsq = fmaf(v.x, v.x, xsq); xsq = fmaf(v.y, v.y, xsq);
        xsq = fmaf(v.z, v.z, xsq); xsq = fmaf(v.w, v.w, xsq);
        xr[4*q+0] = v.x * LOG2E; xr[4*q+1] = v.y * LOG2E;
        xr[4*q+2] = v.z * LOG2E; xr[4*q+3] = v.w * LOG2E;
    }
    const float ai = -0.5f * LOG2E * xsq;
    float acc = 0.0f;
#pragma unroll 2
    for (int j = j0; j < j1; ++j) {
        const float4* cr = (const float4*)(c + (size_t)j * 32);
        const float2 s2 = sw[j - j0];
        float d = ai + s2.x;
#pragma unroll
        for (int q = 0; q < 8; ++q) {
            float4 v = cr[q];
            d = fmaf(xr[4*q+0], v.x, d); d = fmaf(xr[4*q+1], v.y, d);
            d = fmaf(xr[4*q+2], v.z, d); d = fmaf(xr[4*q+3], v.w, d);
        }
        acc = fmaf(s2.y, __builtin_amdgcn_exp2f(d), acc);
    }
    if (valid) atomicAdd(out + i, acc);
}

extern "C" void kernel_launch(void* const* d_in, const int* in_sizes, int n_in,
                              void* d_out, int out_size, void* d_ws, size_t ws_size,
                              hipStream_t stream) {
    const float* x    = (const float*)d_in[0];   // (N, 32)
    const float* c    = (const float*)d_in[1];   // (M, 32)
    const float* beta = (const float*)d_in[2];   // (M,)
    float* out = (float*)d_out;                  // (N,)

    const int N = out_size;                      // 40000
    const int M = in_sizes[2];                   // 4000
    const int JT = (M + 15) / 16;                // 250 j-tiles
    const int SPAN = TPS * JS;                   // tile granularity: 16
    const int JTS = ((JT + SPAN - 1) / SPAN) * SPAN;  // padded: 256
    const int steps = JTS / TPS / JS;            // super-steps per j-split: 16
    const int Mp = JTS * 16;                     // 4096 padded cols

    // ws: chiF (JTS*512 halves, fragment-linear) | sbG (Mp float2)  ~ 288 KB
    const size_t need = (size_t)JTS * 1024 + (size_t)Mp * 8;

    if (ws_size >= need) {
        _Float16* chiF = (_Float16*)d_ws;
        float2*   sbG  = (float2*)(chiF + (size_t)JTS * 512);

        int prep_threads = (Mp * 4 > N) ? Mp * 4 : N;
        prep_c_kernel<<<dim3((prep_threads + 255) / 256), dim3(256), 0, stream>>>(
            c, beta, chiF, sbG, out, M, Mp, N);

        const int itiles = (N + 15) / 16;            // 2500
        const int bx = (itiles + 3) / 4;             // 625 blocks x 4 waves
        krr_mfma_lds_kernel<<<dim3(bx, JS), dim3(256), 0, stream>>>(
            x, chiF, sbG, out, N, steps);

        softplus_kernel<<<dim3((N + 255) / 256), dim3(256), 0, stream>>>(out, N);
    } else {
        zero_out_kernel<<<dim3((N + 255) / 256), dim3(256), 0, stream>>>(out, N);
        int jc = (M + CHUNK_MAX - 1) / CHUNK_MAX;
        if (jc < 8) jc = 8;
        int chunk = (M + jc - 1) / jc;
        dim3 grid((N + 63) / 64, jc);
        krr_partial_kernel<<<grid, dim3(64), 0, stream>>>(x, c, beta, out, N, M, chunk);
        softplus_kernel<<<dim3((N + 255) / 256), dim3(256), 0, stream>>>(out, N);
    }
}

// Round 7
// 91.279 us; speedup vs baseline: 1.8593x; 1.0513x over previous
//
#include <hip/hip_runtime.h>
#include <math.h>
#include <stdint.h>

#define LOG2E 1.44269504088896340736f
#define TPS 8      // j-tiles per super-step (18 KB LDS -> 8 blocks/CU capacity)
#define JS  4      // j-range splits (313x4 blocks -> ~4.9 waves/SIMD)
#define CUT -16.0f // skip exp when ALL 256 tile entries have log2(K) < -16
                   // (K < 1.5e-5; dropped mass ~5e-5 << 1.39e-2 threshold)

typedef _Float16 f16x8 __attribute__((ext_vector_type(8)));
typedef float f32x4 __attribute__((ext_vector_type(4)));

__device__ __forceinline__ float softplus_f(float t) {
    return (t > 20.0f) ? t : log1pf(expf(t));
}

// global -> LDS direct DMA, 16 B/lane. lds base must be wave-uniform; HW adds lane*16.
#define GLDS16(g, l)                                                     \
    __builtin_amdgcn_global_load_lds(                                    \
        (const __attribute__((address_space(1))) uint32_t*)(const void*)(g), \
        (__attribute__((address_space(3))) uint32_t*)(void*)(l), 16, 0, 0)

// ---------------- pass 1: fragment-linear f16 B workspace + out zero-init ----------------
// Tile jt, fragment pos l = q*16+m holds c[j=jt*16+m][k=q*8..q*8+7] as f16 ->
// wave B-load = base + lane*16 B (dense, DMA-compatible).
// sbG[j] = { -0.5*log2e*|c_j|^2, beta_j }; beta=0 on padding kills pad cols.
// Also zeroes out[] (atomicAdd target for the j-split main kernel).
__global__ void prep_c_kernel(const float* __restrict__ c,
                              const float* __restrict__ beta,
                              _Float16* __restrict__ chiF,
                              float2* __restrict__ sbG,
                              float* __restrict__ out,
                              int M, int Mp, int N) {
    int tid = blockIdx.x * blockDim.x + threadIdx.x;
    if (tid < N) out[tid] = 0.0f;

    int j = tid >> 2, q = tid & 3;
    if (j >= Mp) return;
    int jt = j >> 4, m = j & 15;
    size_t fo = (size_t)jt * 512 + (size_t)(q * 16 + m) * 8;   // halves

    float ssq = 0.0f;
    _Float16 hi[8];
    if (j < M) {
        const float4* cp = (const float4*)(c + (size_t)j * 32 + q * 8);
        float4 a = cp[0], b = cp[1];
        float vv[8] = {a.x, a.y, a.z, a.w, b.x, b.y, b.z, b.w};
#pragma unroll
        for (int t = 0; t < 8; ++t) {
            float f = vv[t];
            ssq = fmaf(f, f, ssq);
            hi[t] = (_Float16)f;
        }
    } else {
#pragma unroll
        for (int t = 0; t < 8; ++t) hi[t] = (_Float16)0.0f;
    }
    ssq += __shfl_xor(ssq, 1, 4);       // |c_j|^2 over the 4 q-threads
    ssq += __shfl_xor(ssq, 2, 4);

    *(f16x8*)(chiF + fo) = *(const f16x8*)hi;
    if (q == 0)
        sbG[j] = (j < M) ? make_float2(-0.5f * LOG2E * ssq, beta[j])
                         : make_float2(0.0f, 0.0f);
}

// ---------------- main: LDS-staged MFMA RBF matvec with exp-skip ----------------
// Block = 4 waves; wave w owns TWO i-tiles (rows g*32..g*32+31, g = bx*4+w), so
// each staged B fragment feeds 2 MFMAs (halves LDS read BW per pair — the next
// bottleneck after VALU). blockIdx.y picks a quarter of the j-tiles.
// Exp-skip: K = exp2(acc) with acc ~ -46 typically; a tile needs exp only if
// any entry has acc > CUT (~6% of tiles). Wave-uniform `__any` branch skips the
// 4 v_exp_f32 (16 cy each!) + 4 fma on ~94% of tile-visits.
// C layout (m89): col = lane&15, row = (lane>>4)*4 + reg.
__global__ __launch_bounds__(256) void krr_mfma_lds_kernel(
    const float* __restrict__ x,
    const _Float16* __restrict__ chiF,
    const float2* __restrict__ sbG,
    float* __restrict__ out,
    int N, int steps)             // super-steps per j-split
{
    __shared__ f16x8 chiS[2][TPS][64];                // 16 KB
    __shared__ __align__(16) float2 sbS[2][TPS * 16]; // 2 KB

    const int wave = threadIdx.x >> 6;
    const int lane = threadIdx.x & 63;
    const int m    = lane & 15;
    const int quad = lane >> 4;

    const int g  = blockIdx.x * 4 + wave;    // 32-row group
    const int s0 = blockIdx.y * steps;       // this block's super-step range

    // ---- two A fragments (rows g*32+m and g*32+16+m), pre-scaled by log2e ----
    f16x8 ahi1, ahi2;
    float air1[4], air2[4];
    {
        int rows[2] = {g * 32 + m, g * 32 + 16 + m};
        f16x8* ah[2] = {&ahi1, &ahi2};
        float* ar[2] = {air1, air2};
#pragma unroll
        for (int f = 0; f < 2; ++f) {
            int rc = (rows[f] < N) ? rows[f] : (N - 1);  // clamp load; stores are guarded
            const float4* xp = (const float4*)(x + (size_t)rc * 32 + quad * 8);
            float4 v0 = xp[0], v1 = xp[1];
            float p = v0.x * v0.x + v0.y * v0.y + v0.z * v0.z + v0.w * v0.w
                    + v1.x * v1.x + v1.y * v1.y + v1.z * v1.z + v1.w * v1.w;
            p += __shfl_xor(p, 16, 64);
            p += __shfl_xor(p, 32, 64);               // |x_row|^2 over all quads
            float ai_m = -0.5f * LOG2E * p;
            float vv[8] = {v0.x, v0.y, v0.z, v0.w, v1.x, v1.y, v1.z, v1.w};
#pragma unroll
            for (int t = 0; t < 8; ++t)
                (*ah[f])[t] = (_Float16)(vv[t] * LOG2E);
#pragma unroll
            for (int r = 0; r < 4; ++r)
                ar[f][r] = __shfl(ai_m, quad * 4 + r, 16);  // a_i for C row quad*4+r
        }
    }

    // ---- staging: 8 chi chunks (2/wave) + 1 sb chunk per step ----
    auto stage = [&](int s, int b) {
        const _Float16* base = chiF + (size_t)(s0 + s) * TPS * 512;
#pragma unroll
        for (int ch = wave; ch < TPS; ch += 4)
            GLDS16(base + (size_t)ch * 512 + (size_t)lane * 8, &chiS[b][ch][0]);
        if (wave == 0)
            GLDS16((const char*)(sbG + (size_t)(s0 + s) * (TPS * 16)) + (size_t)lane * 16,
                   &sbS[b][0]);
    };

    stage(0, 0);
    float out1[4] = {0.0f, 0.0f, 0.0f, 0.0f};
    float out2[4] = {0.0f, 0.0f, 0.0f, 0.0f};

    for (int s = 0; s < steps; ++s) {
        const int b = s & 1;
        __syncthreads();                 // drains stage(s) DMA; guards buffer b^1 reuse
        if (s + 1 < steps) stage(s + 1, b ^ 1);

#pragma unroll
        for (int t = 0; t < TPS; ++t) {
            f16x8 bhi = chiS[b][t][lane];             // ds_read_b128, lane-linear
            float2 s2 = sbS[b][t * 16 + m];           // {s_j, beta_j}, broadcast
            f32x4 acc1, acc2;
#pragma unroll
            for (int r = 0; r < 4; ++r) {
                acc1[r] = air1[r] + s2.x;             // fold a_i + s_j into C init
                acc2[r] = air2[r] + s2.x;
            }
            acc1 = __builtin_amdgcn_mfma_f32_16x16x32_f16(ahi1, bhi, acc1, 0, 0, 0);
            acc2 = __builtin_amdgcn_mfma_f32_16x16x32_f16(ahi2, bhi, acc2, 0, 0, 0);

            float mx1 = fmaxf(fmaxf(acc1[0], acc1[1]), fmaxf(acc1[2], acc1[3]));
            float mx2 = fmaxf(fmaxf(acc2[0], acc2[1]), fmaxf(acc2[2], acc2[3]));
            if (__any(mx1 > CUT)) {                   // wave-uniform: s_cbranch skip
#pragma unroll
                for (int r = 0; r < 4; ++r)
                    out1[r] = fmaf(s2.y, __builtin_amdgcn_exp2f(acc1[r]), out1[r]);
            }
            if (__any(mx2 > CUT)) {
#pragma unroll
                for (int r = 0; r < 4; ++r)
                    out2[r] = fmaf(s2.y, __builtin_amdgcn_exp2f(acc2[r]), out2[r]);
            }
        }
    }

    // ---- reduce over 16 cols (lane bits 0..3), atomic partial-sum ----
    float* oas[2] = {out1, out2};
#pragma unroll
    for (int f = 0; f < 2; ++f) {
        const int rowbase = g * 32 + f * 16;
#pragma unroll
        for (int r = 0; r < 4; ++r) {
            float v = oas[f][r];
            v += __shfl_xor(v, 1, 64);
            v += __shfl_xor(v, 2, 64);
            v += __shfl_xor(v, 4, 64);
            v += __shfl_xor(v, 8, 64);
            if (m == r) {
                int row = rowbase + quad * 4 + r;
                if (row < N) atomicAdd(out + row, v);
            }
        }
    }
}

// ---------------- pass 3: softplus over accumulated partials ----------------
__global__ void softplus_kernel(float* __restrict__ out, int n) {
    int i = blockIdx.x * blockDim.x + threadIdx.x;
    if (i < n) out[i] = softplus_f(out[i]);
}

// ---------------- fallback path (ws too small): round-1 VALU kernel ----------------
#define CHUNK_MAX 512
__global__ void zero_out_kernel(float* __restrict__ out, int n) {
    int i = blockIdx.x * blockDim.x + threadIdx.x;
    if (i < n) out[i] = 0.0f;
}
__global__ __launch_bounds__(64, 4) void krr_partial_kernel(
    const float* __restrict__ x, const float* __restrict__ c,
    const float* __restrict__ beta, float* __restrict__ out,
    int N, int M, int chunk)
{
    __shared__ float2 sw[CHUNK_MAX];
    const int lane = threadIdx.x;
    const int j0 = blockIdx.y * chunk;
    const int j1 = min(M, j0 + chunk);
    for (int j = j0 + lane; j < j1; j += 64) {
        const float4* cr = (const float4*)(c + (size_t)j * 32);
        float s = 0.0f;
#pragma unroll
        for (int q = 0; q < 8; ++q) {
            float4 v = cr[q];
            s = fmaf(v.x, v.x, s); s = fmaf(v.y, v.y, s);
            s = fmaf(v.z, v.z, s); s = fmaf(v.w, v.w, s);
        }
        sw[j - j0] = make_float2(-0.5f * LOG2E * s, beta[j]);
    }
    __syncthreads();
    const int i = blockIdx.x * 64 + lane;
    const bool valid = (i < N);
    const float4* xrow = (const float4*)(x + (size_t)(valid ? i : 0) * 32);
    float xr[32]; float xsq = 0.0f;
#pragma unroll
    for (int q = 0; q < 8; ++q) {
        float4 v = xrow[q];
        xsq = fmaf(v.x, v.x, xsq); xsq = fmaf(v.y, v.y, xsq);
        xsq = fmaf(v.z, v.z, xsq); xsq = fmaf(v.w, v.w, xsq);
        xr[4*q+0] = v.x * LOG2E; xr[4*q+1] = v.y * LOG2E;
        xr[4*q+2] = v.z * LOG2E; xr[4*q+3] = v.w * LOG2E;
    }
    const float ai = -0.5f * LOG2E * xsq;
    float acc = 0.0f;
#pragma unroll 2
    for (int j = j0; j < j1; ++j) {
        const float4* cr = (const float4*)(c + (size_t)j * 32);
        const float2 s2 = sw[j - j0];
        float d = ai + s2.x;
#pragma unroll
        for (int q = 0; q < 8; ++q) {
            float4 v = cr[q];
            d = fmaf(xr[4*q+0], v.x, d); d = fmaf(xr[4*q+1], v.y, d);
            d = fmaf(xr[4*q+2], v.z, d); d = fmaf(xr[4*q+3], v.w, d);
        }
        acc = fmaf(s2.y, __builtin_amdgcn_exp2f(d), acc);
    }
    if (valid) atomicAdd(out + i, acc);
}

extern "C" void kernel_launch(void* const* d_in, const int* in_sizes, int n_in,
                              void* d_out, int out_size, void* d_ws, size_t ws_size,
                              hipStream_t stream) {
    const float* x    = (const float*)d_in[0];   // (N, 32)
    const float* c    = (const float*)d_in[1];   // (M, 32)
    const float* beta = (const float*)d_in[2];   // (M,)
    float* out = (float*)d_out;                  // (N,)

    const int N = out_size;                      // 40000
    const int M = in_sizes[2];                   // 4000
    const int JT = (M + 15) / 16;                // 250 j-tiles
    const int SPAN = TPS * JS;                   // tile granularity: 32
    const int JTS = ((JT + SPAN - 1) / SPAN) * SPAN;  // padded: 256
    const int steps = JTS / SPAN;                // super-steps per j-split: 8
    const int Mp = JTS * 16;                     // 4096 padded cols

    // ws: chiF (JTS*512 halves, fragment-linear) | sbG (Mp float2)  ~ 288 KB
    const size_t need = (size_t)JTS * 1024 + (size_t)Mp * 8;

    if (ws_size >= need) {
        _Float16* chiF = (_Float16*)d_ws;
        float2*   sbG  = (float2*)(chiF + (size_t)JTS * 512);

        int prep_threads = (Mp * 4 > N) ? Mp * 4 : N;
        prep_c_kernel<<<dim3((prep_threads + 255) / 256), dim3(256), 0, stream>>>(
            c, beta, chiF, sbG, out, M, Mp, N);

        const int groups = (N + 31) / 32;            // 1250 32-row groups
        const int bx = (groups + 3) / 4;             // 313 blocks x 4 waves
        krr_mfma_lds_kernel<<<dim3(bx, JS), dim3(256), 0, stream>>>(
            x, chiF, sbG, out, N, steps);

        softplus_kernel<<<dim3((N + 255) / 256), dim3(256), 0, stream>>>(out, N);
    } else {
        zero_out_kernel<<<dim3((N + 255) / 256), dim3(256), 0, stream>>>(out, N);
        int jc = (M + CHUNK_MAX - 1) / CHUNK_MAX;
        if (jc < 8) jc = 8;
        int chunk = (M + jc - 1) / jc;
        dim3 grid((N + 63) / 64, jc);
        krr_partial_kernel<<<grid, dim3(64), 0, stream>>>(x, c, beta, out, N, M, chunk);
        softplus_kernel<<<dim3((N + 255) / 256), dim3(256), 0, stream>>>(out, N);
    }
}